// Round 8
// baseline (775.864 us; speedup 1.0000x reference)
//
#include <hip/hip_runtime.h>

typedef __attribute__((ext_vector_type(4))) float f32x4;
typedef __attribute__((ext_vector_type(8))) short bf16x8;
typedef __attribute__((ext_vector_type(4))) unsigned short u16x4;
typedef unsigned short u16;

// Static device intermediates (BSS; fully rewritten every launch).
__device__ static u16   g_xh[(size_t)50176 * 768];     // bf16(x)            77 MB
__device__ static u16   g_wqkvh[(size_t)2304 * 768];   // bf16(w_qkv)       3.5 MB
__device__ static u16   g_wprojh[(size_t)768 * 768];   // bf16(w_proj)      1.2 MB
__device__ static u16   g_qkv[(size_t)50176 * 2304];   // qkv bf16          231 MB
__device__ static u16   g_g1[(size_t)48 * 784 * 256];  // conv1 out bf16     19 MB
__device__ static u16   g_g2[(size_t)48 * 196 * 256];  // conv2 out bf16    4.8 MB
__device__ static u16   g_fh[(size_t)50176 * 768];     // fused bf16         77 MB

static __device__ __forceinline__ u16 f2bf(float x){
  unsigned u = __float_as_uint(x);
  u += 0x7fffu + ((u >> 16) & 1u);
  return (u16)(u >> 16);
}
static __device__ __forceinline__ float bf2f(u16 h){
  return __uint_as_float(((unsigned)h) << 16);
}

// Merged f32 -> bf16 (RNE) for three arrays, vectorized x4, grid-stride.
__global__ __launch_bounds__(256)
void cvt_bf16_3(const float* __restrict__ i0, u16* __restrict__ o0, int n0,
                const float* __restrict__ i1, u16* __restrict__ o1, int n1,
                const float* __restrict__ i2, u16* __restrict__ o2, int n2)
{
  const int total = n0 + n1 + n2;
  int i = blockIdx.x * blockDim.x + threadIdx.x;
  const int stride = gridDim.x * blockDim.x;
  for (; i < total; i += stride) {
    const float* in; u16* out; int j = i;
    if (j < n0)           { in = i0; out = o0; }
    else if (j < n0 + n1) { in = i1; out = o1; j -= n0; }
    else                  { in = i2; out = o2; j -= n0 + n1; }
    const f32x4 v = ((const f32x4*)in)[j];
    u16x4 o;
    #pragma unroll
    for (int k = 0; k < 4; k++) o[k] = f2bf(v[k]);
    ((u16x4*)out)[j] = o;
  }
}

// ---------------------------------------------------------------------------
// 128x128-tile GEMM, 4 waves (2x2), BK=32, 3 LDS slots (48KB -> 3 blocks/CU),
// lead-1 counted-vmcnt pipeline: per step {STAGE(t+1); vmcnt(4); s_barrier;
// ds_read + 16 MFMA}. vmcnt never drains to 0 in-loop; cross-block TLP
// (3 blocks/CU) fills sync bubbles.  C = A * B^T (+bias).
//
// LDS slot: A [128 rows][32 bf16] at +0 (8KB), B same at +8192.
// Pair-packed rows (R6-verified, 0 conflicts): phys row pr=r>>1 (128B),
// chunk p = (((r&1)<<2)+cc) ^ (pr&7); staging source inverse-swizzled so the
// linear global_load_lds (thread->byte tid*16 / +4096) lands correctly.
// ---------------------------------------------------------------------------
template<bool BIAS, typename OUT_T>
__global__ __launch_bounds__(256, 3)
void gemm3s(const u16* __restrict__ A0, const u16* __restrict__ Bw,
            const float* __restrict__ bias, OUT_T* __restrict__ C,
            int N, int K, int GX)
{
  __shared__ __align__(16) char ldsb[3 * 16384];
  const int tid = threadIdx.x;
  const int lane = tid & 63;
  const int w = tid >> 6;
  const int wm = w >> 1, wn = w & 1;
  const int l15 = lane & 15, l4 = lane >> 4;

  // T1 bijective XCD swizzle (m204).
  const int nwg = gridDim.x;
  const int bid = blockIdx.x;
  const int q8 = nwg >> 3, r8 = nwg & 7;
  const int xcd = bid & 7, lid = bid >> 3;
  const int swz = (xcd < r8 ? xcd * (q8 + 1) : r8 * (q8 + 1) + (xcd - r8) * q8) + lid;
  const int bn = swz % GX;
  const int bm = swz / GX;

  // ---- staging source precompute (inverse swizzle; 2 slots/thread/operand)
  const int pr0 = tid >> 3, sp0 = tid & 7;
  const int tt0 = sp0 ^ (pr0 & 7);
  const int row0 = pr0 * 2 + (tt0 >> 2), col0 = (tt0 & 3) * 8;
  const int s1 = tid + 256;
  const int pr1 = s1 >> 3, sp1 = s1 & 7;
  const int tt1 = sp1 ^ (pr1 & 7);
  const int row1 = pr1 * 2 + (tt1 >> 2), col1 = (tt1 & 3) * 8;

  const u16* pa0 = A0 + (size_t)(bm * 128 + row0) * K + col0;
  const u16* pa1 = A0 + (size_t)(bm * 128 + row1) * K + col1;
  const u16* pb0 = Bw + (size_t)(bn * 128 + row0) * K + col0;
  const u16* pb1 = Bw + (size_t)(bn * 128 + row1) * K + col1;

  #define GLDS(srcp, ldsoff) __builtin_amdgcn_global_load_lds( \
      (__attribute__((address_space(1))) const void*)(srcp),   \
      (__attribute__((address_space(3))) void*)(ldsb + (ldsoff)), 16, 0, 0)

  auto STAGE = [&](int slot, int t) {
    const int base = slot * 16384;
    const int ko = t * 32;
    GLDS(pa0 + ko, base + tid * 16);
    GLDS(pa1 + ko, base + 4096 + tid * 16);
    GLDS(pb0 + ko, base + 8192 + tid * 16);
    GLDS(pb1 + ko, base + 12288 + tid * 16);
  };

  f32x4 acc[4][4];
  #pragma unroll
  for (int i = 0; i < 4; i++)
    #pragma unroll
    for (int j = 0; j < 4; j++) acc[i][j] = (f32x4)0.f;

  auto COMPUTE = [&](int slot) {
    const char* base = ldsb + slot * 16384;
    bf16x8 afr[4], bfr[4];
    #pragma unroll
    for (int mi = 0; mi < 4; mi++) {
      const int r = wm * 64 + mi * 16 + l15;
      const int pr = r >> 1;
      const int p = (((r & 1) << 2) + l4) ^ (pr & 7);
      afr[mi] = *(const bf16x8*)(base + pr * 128 + p * 16);
    }
    #pragma unroll
    for (int ni = 0; ni < 4; ni++) {
      const int r = wn * 64 + ni * 16 + l15;
      const int pr = r >> 1;
      const int p = (((r & 1) << 2) + l4) ^ (pr & 7);
      bfr[ni] = *(const bf16x8*)(base + 8192 + pr * 128 + p * 16);
    }
    #pragma unroll
    for (int mi = 0; mi < 4; mi++)
      #pragma unroll
      for (int ni = 0; ni < 4; ni++)
        acc[mi][ni] = __builtin_amdgcn_mfma_f32_16x16x32_bf16(afr[mi], bfr[ni], acc[mi][ni], 0, 0, 0);
  };

  const int T = K >> 5;   // K/32 steps
  STAGE(0, 0);
  int rs = 0, ws = 1;
  for (int t = 0; t < T; ++t) {
    if (t + 1 < T) {
      STAGE(ws, t + 1);
      asm volatile("s_waitcnt vmcnt(4)" ::: "memory");
    } else {
      asm volatile("s_waitcnt vmcnt(0)" ::: "memory");
    }
    __builtin_amdgcn_sched_barrier(0);
    __builtin_amdgcn_s_barrier();
    __builtin_amdgcn_sched_barrier(0);
    COMPUTE(rs);
    rs = (rs == 2) ? 0 : rs + 1;
    ws = (ws == 2) ? 0 : ws + 1;
  }
  #undef GLDS

  // ---- epilogue (R5-verified mapping) ----
  #pragma unroll
  for (int mi = 0; mi < 4; mi++)
    #pragma unroll
    for (int ni = 0; ni < 4; ni++) {
      const int col = bn * 128 + wn * 64 + ni * 16 + l15;
      const float bv = BIAS ? bias[col] : 0.f;
      #pragma unroll
      for (int reg = 0; reg < 4; reg++) {
        const int row = bm * 128 + wm * 64 + mi * 16 + (l4 << 2) + reg;
        const float val = acc[mi][ni][reg] + bv;
        if constexpr (sizeof(OUT_T) == 2) C[(size_t)row * N + col] = (OUT_T)f2bf(val);
        else                              C[(size_t)row * N + col] = val;
      }
    }
}

// Grouped conv3x3 stride-1 + bias + 2x2 maxpool -> bf16 (4x4 register patch).
__global__ __launch_bounds__(256)
void conv_pool1(const u16* __restrict__ qkv, const float* __restrict__ wsrc,
                const float* __restrict__ bias, u16* __restrict__ gout)
{
  __shared__ float wl[64 * 145];
  const int g = threadIdx.x;
  const int ty = threadIdx.y;
  const int tid = ty * 64 + g;
  for (int i = tid; i < 9216; i += 256) {
    const int oc = i / 36, rem = i - oc * 36;
    wl[(oc >> 2) * 145 + (oc & 3) * 36 + rem] = wsrc[i];
  }
  __syncthreads();

  const int bt = blockIdx.x;
  const int b = bt / 3, t = bt - b * 3;
  const int p = blockIdx.y * 4 + ty;
  const int y = p / 28, x = p - y * 28;
  const float* wg = &wl[g * 145];

  f32x4 f[4][4];
  #pragma unroll
  for (int i = 0; i < 4; i++) {
    const int iy = 2 * y - 1 + i;
    #pragma unroll
    for (int k = 0; k < 4; k++) {
      const int ix = 2 * x - 1 + k;
      f32x4 v = (f32x4)0.f;
      if (iy >= 0 && iy < 56 && ix >= 0 && ix < 56) {
        const u16x4 in4 = *(const u16x4*)&qkv[(size_t)(b * 3136 + iy * 56 + ix) * 2304 + t * 768 + 256 + g * 4];
        v[0] = bf2f(in4[0]); v[1] = bf2f(in4[1]); v[2] = bf2f(in4[2]); v[3] = bf2f(in4[3]);
      }
      f[i][k] = v;
    }
  }

  const f32x4 bias4 = *(const f32x4*)&bias[g * 4];
  f32x4 best;
  #pragma unroll
  for (int j = 0; j < 4; j++) best[j] = -3.4e38f;

  #pragma unroll
  for (int dy = 0; dy < 2; dy++)
    #pragma unroll
    for (int dx = 0; dx < 2; dx++) {
      f32x4 c4 = bias4;
      #pragma unroll
      for (int ky = 0; ky < 3; ky++)
        #pragma unroll
        for (int kx = 0; kx < 3; kx++) {
          const f32x4 in4 = f[dy + ky][dx + kx];
          #pragma unroll
          for (int oc = 0; oc < 4; oc++) {
            const float* wp = &wg[oc * 36 + ky * 3 + kx];
            c4[oc] += in4[0] * wp[0] + in4[1] * wp[9] + in4[2] * wp[18] + in4[3] * wp[27];
          }
        }
      #pragma unroll
      for (int j = 0; j < 4; j++) best[j] = fmaxf(best[j], c4[j]);
    }
  u16x4 o4;
  #pragma unroll
  for (int j = 0; j < 4; j++) o4[j] = f2bf(best[j]);
  *(u16x4*)&gout[((size_t)bt * 784 + p) * 256 + g * 4] = o4;
}

// Generic grouped conv3x3 + bias + 2x2 maxpool -> bf16 (scale 2).
__global__ __launch_bounds__(256)
void conv_pool(const u16* __restrict__ qkv, const float* __restrict__ wsrc,
               const float* __restrict__ bias, u16* __restrict__ gout,
               int chan0, int Pout, int st, int pd, int dl)
{
  __shared__ float wl[64 * 145];
  const int g = threadIdx.x;
  const int ty = threadIdx.y;
  const int tid = ty * 64 + g;
  for (int i = tid; i < 9216; i += 256) {
    const int oc = i / 36, rem = i - oc * 36;
    wl[(oc >> 2) * 145 + (oc & 3) * 36 + rem] = wsrc[i];
  }
  __syncthreads();

  const int bt = blockIdx.x;
  const int b = bt / 3, t = bt - b * 3;
  const int total = Pout * Pout;
  const int p = blockIdx.y * 4 + ty;
  if (p >= total) return;
  const int y = p / Pout, x = p - y * Pout;

  const f32x4 bias4 = *(const f32x4*)&bias[g * 4];
  f32x4 best;
  #pragma unroll
  for (int j = 0; j < 4; j++) best[j] = -3.4e38f;
  const float* wg = &wl[g * 145];

  #pragma unroll
  for (int dy = 0; dy < 2; dy++)
    #pragma unroll
    for (int dx = 0; dx < 2; dx++) {
      const int py = 2 * y + dy, px = 2 * x + dx;
      f32x4 c4 = bias4;
      #pragma unroll
      for (int ky = 0; ky < 3; ky++) {
        const int iy = py * st - pd + ky * dl;
        if (iy < 0 || iy >= 56) continue;
        #pragma unroll
        for (int kx = 0; kx < 3; kx++) {
          const int ix = px * st - pd + kx * dl;
          if (ix < 0 || ix >= 56) continue;
          const u16x4 in4 = *(const u16x4*)&qkv[(size_t)(b * 3136 + iy * 56 + ix) * 2304 + t * 768 + chan0 + g * 4];
          const float f0 = bf2f(in4[0]), f1 = bf2f(in4[1]), f2 = bf2f(in4[2]), f3 = bf2f(in4[3]);
          #pragma unroll
          for (int oc = 0; oc < 4; oc++) {
            const float* wp = &wg[oc * 36 + ky * 3 + kx];
            c4[oc] += f0 * wp[0] + f1 * wp[9] + f2 * wp[18] + f3 * wp[27];
          }
        }
      }
      #pragma unroll
      for (int j = 0; j < 4; j++) best[j] = fmaxf(best[j], c4[j]);
    }
  u16x4 o4;
  #pragma unroll
  for (int j = 0; j < 4; j++) o4[j] = f2bf(best[j]);
  *(u16x4*)&gout[((size_t)bt * total + p) * 256 + g * 4] = o4;
}

// MFMA windowed attention: one WAVE per (b, region, head); 4 waves/block.
template<int SRC>
__global__ __launch_bounds__(256)
void attn_mfma(const u16* __restrict__ src, u16* __restrict__ fh,
               int side, int Hs, int head_base, int rep)
{
  __shared__ __align__(16) u16 sV[4][64 * 64];
  __shared__ __align__(16) u16 sP[4][64 * 64];
  const int tid = threadIdx.x;
  const int lane = tid & 63;
  const int w = tid >> 6;
  const int nreg = side * side;
  int unit = blockIdx.x * 4 + w;
  const int h = unit & 3; unit >>= 2;
  const int r = unit % nreg;
  const int b = unit / nreg;
  const int hr = r / side, wr = r - hr * side;
  const int l15 = lane & 15, l4 = lane >> 4;

  char* vb = (char*)sV[w];
  char* pb = (char*)sP[w];

  auto gidx = [&](int t, int pp, int c) -> size_t {
    const int py = pp / 7, px = pp - py * 7;
    const int yy = hr * 7 + py, xx = wr * 7 + px;
    if (SRC == 0) return ((size_t)(b * 3136 + yy * 56 + xx)) * 2304 + (size_t)(t * 768 + h * 64 + c);
    else          return ((size_t)(b * 3 + t)) * ((size_t)Hs * Hs * 256) + (size_t)(yy * Hs + xx) * 256 + h * 64 + c;
  };

  // ---- stage V (t=2), rows clamped; swizzle byte ^= ((q>>3)&3)<<5 ----
  for (int i = lane; i < 1024; i += 64) {
    const int q = i >> 4, dc = i & 15;
    const int qs = q > 48 ? 48 : q;
    const u16x4 v4 = *(const u16x4*)&src[gidx(2, qs, dc * 4)];
    *(u16x4*)(vb + ((q * 128 + dc * 8) ^ (((q >> 3) & 3) << 5))) = v4;
  }

  // ---- QK^T ----
  f32x4 s[4][4];
  #pragma unroll
  for (int i = 0; i < 4; i++)
    #pragma unroll
    for (int j = 0; j < 4; j++) s[i][j] = (f32x4)0.f;

  bf16x8 bk[4][2];
  #pragma unroll
  for (int ni = 0; ni < 4; ni++) {
    const int q = ni * 16 + l15;
    const int qs = q > 48 ? 48 : q;
    #pragma unroll
    for (int ks = 0; ks < 2; ks++)
      bk[ni][ks] = *(const bf16x8*)&src[gidx(1, qs, ks * 32 + l4 * 8)];
  }
  #pragma unroll
  for (int mi = 0; mi < 4; mi++) {
    const int p = mi * 16 + l15;
    const int ps = p > 48 ? 48 : p;
    const bf16x8 a0 = *(const bf16x8*)&src[gidx(0, ps, l4 * 8)];
    const bf16x8 a1 = *(const bf16x8*)&src[gidx(0, ps, 32 + l4 * 8)];
    #pragma unroll
    for (int ni = 0; ni < 4; ni++) {
      s[mi][ni] = __builtin_amdgcn_mfma_f32_16x16x32_bf16(a0, bk[ni][0], s[mi][ni], 0, 0, 0);
      s[mi][ni] = __builtin_amdgcn_mfma_f32_16x16x32_bf16(a1, bk[ni][1], s[mi][ni], 0, 0, 0);
    }
  }

  // ---- mask cols q>=49, in-register softmax (unnormalized P) ----
  #pragma unroll
  for (int ni = 0; ni < 4; ni++) {
    const bool bad = (ni * 16 + l15) > 48;
    #pragma unroll
    for (int mi = 0; mi < 4; mi++)
      #pragma unroll
      for (int reg = 0; reg < 4; reg++)
        s[mi][ni][reg] = bad ? -1e30f : s[mi][ni][reg];
  }

  float inv[4][4];
  #pragma unroll
  for (int mi = 0; mi < 4; mi++)
    #pragma unroll
    for (int reg = 0; reg < 4; reg++) {
      float m = fmaxf(fmaxf(s[mi][0][reg], s[mi][1][reg]), fmaxf(s[mi][2][reg], s[mi][3][reg]));
      m = fmaxf(m, __shfl_xor(m, 1));
      m = fmaxf(m, __shfl_xor(m, 2));
      m = fmaxf(m, __shfl_xor(m, 4));
      m = fmaxf(m, __shfl_xor(m, 8));
      float partial = 0.f;
      #pragma unroll
      for (int ni = 0; ni < 4; ni++) {
        const float e = __expf((s[mi][ni][reg] - m) * 0.125f);
        s[mi][ni][reg] = e;
        partial += e;
      }
      partial += __shfl_xor(partial, 1);
      partial += __shfl_xor(partial, 2);
      partial += __shfl_xor(partial, 4);
      partial += __shfl_xor(partial, 8);
      inv[mi][reg] = 1.f / partial;
    }

  // ---- P -> LDS (bf16, XOR-swizzled rows) ----
  #pragma unroll
  for (int mi = 0; mi < 4; mi++)
    #pragma unroll
    for (int ni = 0; ni < 4; ni++)
      #pragma unroll
      for (int reg = 0; reg < 4; reg++) {
        const int row = mi * 16 + l4 * 4 + reg;
        const int col = ni * 16 + l15;
        *(u16*)(pb + ((row * 128 + col * 2) ^ ((row & 7) << 4))) = f2bf(s[mi][ni][reg]);
      }
  __syncthreads();

  // ---- PV ----
  f32x4 o[4][4];
  #pragma unroll
  for (int i = 0; i < 4; i++)
    #pragma unroll
    for (int j = 0; j < 4; j++) o[i][j] = (f32x4)0.f;

  #pragma unroll
  for (int ks = 0; ks < 2; ks++) {
    bf16x8 bv[4];
    #pragma unroll
    for (int ni = 0; ni < 4; ni++)
      #pragma unroll
      for (int j = 0; j < 8; j++) {
        const int q = ks * 32 + l4 * 8 + j;
        bv[ni][j] = *(const short*)(vb + ((q * 128 + (ni * 16 + l15) * 2) ^ (((q >> 3) & 3) << 5)));
      }
    #pragma unroll
    for (int mi = 0; mi < 4; mi++) {
      const int row = mi * 16 + l15;
      const bf16x8 pa = *(const bf16x8*)(pb + ((row * 128 + (ks * 4 + l4) * 16) ^ ((row & 7) << 4)));
      #pragma unroll
      for (int ni = 0; ni < 4; ni++)
        o[mi][ni] = __builtin_amdgcn_mfma_f32_16x16x32_bf16(pa, bv[ni], o[mi][ni], 0, 0, 0);
    }
  }

  // ---- epilogue: scale by 1/sum, bf16, replicate ----
  const int head = head_base + h;
  #pragma unroll
  for (int mi = 0; mi < 4; mi++)
    #pragma unroll
    for (int reg = 0; reg < 4; reg++) {
      const int p = mi * 16 + l4 * 4 + reg;
      if (p >= 49) continue;
      const float iv = inv[mi][reg];
      u16 hv[4];
      #pragma unroll
      for (int ni = 0; ni < 4; ni++) hv[ni] = f2bf(o[mi][ni][reg] * iv);
      for (int m = 0; m < rep; m++) {
        const size_t ob = ((size_t)b * 3136 + (size_t)(m * nreg + r) * 49 + p) * 768 + head * 64 + l15;
        #pragma unroll
        for (int ni = 0; ni < 4; ni++) fh[ob + ni * 16] = hv[ni];
      }
    }
}

extern "C" void kernel_launch(void* const* d_in, const int* in_sizes, int n_in,
                              void* d_out, int out_size, void* d_ws, size_t ws_size,
                              hipStream_t stream)
{
  const float* x      = (const float*)d_in[0];
  const float* w_qkv  = (const float*)d_in[1];
  const float* w_proj = (const float*)d_in[2];
  const float* b_proj = (const float*)d_in[3];
  const float* c1w    = (const float*)d_in[4];
  const float* c1b    = (const float*)d_in[5];
  const float* c2w    = (const float*)d_in[6];
  const float* c2b    = (const float*)d_in[7];
  float* out = (float*)d_out;

  u16 *xh, *wqkvh, *wprojh, *qkvb, *g1, *g2, *fh;
  hipGetSymbolAddress((void**)&xh,     HIP_SYMBOL(g_xh));
  hipGetSymbolAddress((void**)&wqkvh,  HIP_SYMBOL(g_wqkvh));
  hipGetSymbolAddress((void**)&wprojh, HIP_SYMBOL(g_wprojh));
  hipGetSymbolAddress((void**)&qkvb,   HIP_SYMBOL(g_qkv));
  hipGetSymbolAddress((void**)&g1,     HIP_SYMBOL(g_g1));
  hipGetSymbolAddress((void**)&g2,     HIP_SYMBOL(g_g2));
  hipGetSymbolAddress((void**)&fh,     HIP_SYMBOL(g_fh));

  // 0) one-shot bf16 conversions (merged launch)
  cvt_bf16_3<<<2048, 256, 0, stream>>>(x, xh, 50176 * 768 / 4,
                                       w_qkv, wqkvh, 2304 * 768 / 4,
                                       w_proj, wprojh, 768 * 768 / 4);

  // 1) QKV GEMM (bf16): (50176,768)@(2304,768)^T -> qkv bf16
  gemm3s<false, u16><<<(50176 / 128) * (2304 / 128), 256, 0, stream>>>(
      xh, wqkvh, nullptr, qkvb, 2304, 768, 2304 / 128);

  // 2) convs for scales 1 and 2 (bf16 out)
  conv_pool1<<<dim3(48, 196), dim3(64, 4), 0, stream>>>(qkvb, c1w, c1b, g1);
  conv_pool<<<dim3(48, 49),  dim3(64, 4), 0, stream>>>(qkvb, c2w, c2b, g2, 512, 14, 2, 2, 2);

  // 3) MFMA windowed attention per scale -> fused bf16
  attn_mfma<0><<<16 * 64 * 4 / 4, 256, 0, stream>>>(qkvb, fh, 8, 56, 0, 1);
  attn_mfma<1><<<16 * 16 * 4 / 4, 256, 0, stream>>>(g1,   fh, 4, 28, 4, 4);
  attn_mfma<1><<<16 * 4 * 4 / 4,  256, 0, stream>>>(g2,   fh, 2, 14, 8, 16);

  // 4) proj GEMM + bias -> out (f32)
  gemm3s<true, float><<<(50176 / 128) * (768 / 128), 256, 0, stream>>>(
      fh, wprojh, b_proj, out, 768, 768, 768 / 128);
}

// Round 9
// 616.117 us; speedup vs baseline: 1.2593x; 1.2593x over previous
//
#include <hip/hip_runtime.h>

typedef __attribute__((ext_vector_type(4))) float f32x4;
typedef __attribute__((ext_vector_type(8))) short bf16x8;
typedef __attribute__((ext_vector_type(4))) unsigned short u16x4;
typedef unsigned short u16;

// Static device intermediates (BSS; fully rewritten every launch).
__device__ static u16   g_xh[(size_t)50176 * 768];     // bf16(x)            77 MB
__device__ static u16   g_wqkvh[(size_t)2304 * 768];   // bf16(w_qkv)       3.5 MB
__device__ static u16   g_wprojh[(size_t)768 * 768];   // bf16(w_proj)      1.2 MB
__device__ static u16   g_qkv[(size_t)50176 * 2304];   // qkv bf16          231 MB
__device__ static u16   g_g1[(size_t)48 * 784 * 256];  // conv1 out bf16     19 MB
__device__ static u16   g_g2[(size_t)48 * 196 * 256];  // conv2 out bf16    4.8 MB
__device__ static u16   g_fh[(size_t)50176 * 768];     // fused bf16         77 MB

static __device__ __forceinline__ u16 f2bf(float x){
  unsigned u = __float_as_uint(x);
  u += 0x7fffu + ((u >> 16) & 1u);
  return (u16)(u >> 16);
}
static __device__ __forceinline__ float bf2f(u16 h){
  return __uint_as_float(((unsigned)h) << 16);
}

// Merged f32 -> bf16 (RNE) for three arrays, vectorized x4, grid-stride.
__global__ __launch_bounds__(256)
void cvt_bf16_3(const float* __restrict__ i0, u16* __restrict__ o0, int n0,
                const float* __restrict__ i1, u16* __restrict__ o1, int n1,
                const float* __restrict__ i2, u16* __restrict__ o2, int n2)
{
  const int total = n0 + n1 + n2;
  int i = blockIdx.x * blockDim.x + threadIdx.x;
  const int stride = gridDim.x * blockDim.x;
  for (; i < total; i += stride) {
    const float* in; u16* out; int j = i;
    if (j < n0)           { in = i0; out = o0; }
    else if (j < n0 + n1) { in = i1; out = o1; j -= n0; }
    else                  { in = i2; out = o2; j -= n0 + n1; }
    const f32x4 v = ((const f32x4*)in)[j];
    u16x4 o;
    #pragma unroll
    for (int k = 0; k < 4; k++) o[k] = f2bf(v[k]);
    ((u16x4*)out)[j] = o;
  }
}

// ---------------------------------------------------------------------------
// R6-verified 256x256-tile GEMM, 8 waves (2x4), BK=32, 4 LDS buffers,
// counted-vmcnt pipeline (lead-2, vmcnt(8), never drained in-loop).
// C = A * B^T (+bias).  Measured: 215 us QKV (826 TF), 0 bank conflicts.
// ---------------------------------------------------------------------------
template<bool BIAS, typename OUT_T>
__global__ __launch_bounds__(512, 2)
void gemm256(const u16* __restrict__ A0, const u16* __restrict__ Bw,
             const float* __restrict__ bias, OUT_T* __restrict__ C,
             int N, int K, int GX)
{
  __shared__ __align__(16) char ldsb[4 * 32768];   // 4 buf x (A 16K + B 16K)
  const int tid = threadIdx.x;
  const int lane = tid & 63;
  const int w = tid >> 6;          // 0..7
  const int wm = w >> 2;           // 0..1 : row half (128 rows)
  const int wn = w & 3;            // 0..3 : col quarter (64 cols)
  const int l15 = lane & 15, l4 = lane >> 4;

  // T1 bijective XCD swizzle (m204).
  const int nwg = gridDim.x;
  const int bid = blockIdx.x;
  const int q8 = nwg >> 3, r8 = nwg & 7;
  const int xcd = bid & 7, lid = bid >> 3;
  const int swz = (xcd < r8 ? xcd * (q8 + 1) : r8 * (q8 + 1) + (xcd - r8) * q8) + lid;
  const int bn = swz % GX;
  const int bm = swz / GX;

  // ---- staging source precompute (inverse swizzle) ----
  const int sq = tid >> 3;                 // physical row within 64-row half
  const int sp = tid & 7;                  // physical chunk
  const int tt = sp ^ (sq & 7);
  const int sa = tt >> 2, scc = tt & 3;
  const int srow0 = sq * 2 + sa;           // logical row (half 0)
  const u16* a0 = A0 + (size_t)(bm * 256 + srow0) * K + scc * 8;
  const u16* a1 = A0 + (size_t)(bm * 256 + 128 + srow0) * K + scc * 8;
  const u16* b0 = Bw + (size_t)(bn * 256 + srow0) * K + scc * 8;
  const u16* b1 = Bw + (size_t)(bn * 256 + 128 + srow0) * K + scc * 8;
  const int wofs = w << 10;

  #define GLDS(srcp, ldsoff) __builtin_amdgcn_global_load_lds( \
      (__attribute__((address_space(1))) const void*)(srcp),   \
      (__attribute__((address_space(3))) void*)(ldsb + (ldsoff)), 16, 0, 0)

  auto STAGE = [&](int s) {
    const int bb = (s & 3) << 15;
    const int ko = s * 32;
    GLDS(a0 + ko, bb + wofs);
    GLDS(a1 + ko, bb + 8192 + wofs);
    GLDS(b0 + ko, bb + 16384 + wofs);
    GLDS(b1 + ko, bb + 24576 + wofs);
  };

  f32x4 acc[8][4];
  #pragma unroll
  for (int i = 0; i < 8; i++)
    #pragma unroll
    for (int j = 0; j < 4; j++) acc[i][j] = (f32x4)0.f;

  auto COMPUTE = [&](int t) {
    const char* base = ldsb + ((t & 3) << 15);
    bf16x8 bfr[4], afr[8];
    #pragma unroll
    for (int ni = 0; ni < 4; ni++) {
      const int r = wn * 64 + ni * 16 + l15;
      const int pr = r >> 1;
      const int p = (((r & 1) << 2) + l4) ^ (pr & 7);
      bfr[ni] = *(const bf16x8*)(base + 16384 + pr * 128 + p * 16);
    }
    #pragma unroll
    for (int mi = 0; mi < 8; mi++) {
      const int r = wm * 128 + mi * 16 + l15;
      const int pr = r >> 1;
      const int p = (((r & 1) << 2) + l4) ^ (pr & 7);
      afr[mi] = *(const bf16x8*)(base + pr * 128 + p * 16);
    }
    __builtin_amdgcn_s_setprio(1);
    #pragma unroll
    for (int mi = 0; mi < 8; mi++)
      #pragma unroll
      for (int ni = 0; ni < 4; ni++)
        acc[mi][ni] = __builtin_amdgcn_mfma_f32_16x16x32_bf16(afr[mi], bfr[ni], acc[mi][ni], 0, 0, 0);
    __builtin_amdgcn_s_setprio(0);
  };

  const int T = K >> 5;   // K/32 steps
  STAGE(0);
  STAGE(1);
  for (int t = 0; t < T - 2; ++t) {
    STAGE(t + 2);
    asm volatile("s_waitcnt vmcnt(8)" ::: "memory");
    __builtin_amdgcn_sched_barrier(0);
    __builtin_amdgcn_s_barrier();
    __builtin_amdgcn_sched_barrier(0);
    COMPUTE(t);
  }
  asm volatile("s_waitcnt vmcnt(4)" ::: "memory");
  __builtin_amdgcn_sched_barrier(0);
  __builtin_amdgcn_s_barrier();
  __builtin_amdgcn_sched_barrier(0);
  COMPUTE(T - 2);
  asm volatile("s_waitcnt vmcnt(0)" ::: "memory");
  __builtin_amdgcn_sched_barrier(0);
  __builtin_amdgcn_s_barrier();
  __builtin_amdgcn_sched_barrier(0);
  COMPUTE(T - 1);
  #undef GLDS

  // ---- epilogue ----
  #pragma unroll
  for (int mi = 0; mi < 8; mi++)
    #pragma unroll
    for (int ni = 0; ni < 4; ni++) {
      const int col = bn * 256 + wn * 64 + ni * 16 + l15;
      const float bv = BIAS ? bias[col] : 0.f;
      #pragma unroll
      for (int reg = 0; reg < 4; reg++) {
        const int row = bm * 256 + wm * 128 + mi * 16 + (l4 << 2) + reg;
        const float val = acc[mi][ni][reg] + bv;
        if constexpr (sizeof(OUT_T) == 2) C[(size_t)row * N + col] = (OUT_T)f2bf(val);
        else                              C[(size_t)row * N + col] = val;
      }
    }
}

// ---------------------------------------------------------------------------
// Merged grouped-conv3x3 + bias + 2x2 maxpool for BOTH scales (one launch).
// blockIdx.y < 196 -> scale1 (stride1/pad1/dil1, 28x28, 4x4 reg patch);
// else             -> scale2 (stride2/pad2/dil2, 14x14).
// ---------------------------------------------------------------------------
__global__ __launch_bounds__(256)
void conv_all(const u16* __restrict__ qkv,
              const float* __restrict__ c1w, const float* __restrict__ c1b,
              u16* __restrict__ g1,
              const float* __restrict__ c2w, const float* __restrict__ c2b,
              u16* __restrict__ g2)
{
  __shared__ float wl[64 * 145];
  const int g = threadIdx.x;
  const int ty = threadIdx.y;
  const int tid = ty * 64 + g;
  const int bt = blockIdx.x;
  const int b = bt / 3, t = bt - b * 3;
  const bool is1 = blockIdx.y < 196;

  const float* wsrc = is1 ? c1w : c2w;
  for (int i = tid; i < 9216; i += 256) {
    const int oc = i / 36, rem = i - oc * 36;
    wl[(oc >> 2) * 145 + (oc & 3) * 36 + rem] = wsrc[i];
  }
  __syncthreads();
  const float* wg = &wl[g * 145];

  if (is1) {
    const int p = blockIdx.y * 4 + ty;
    const int y = p / 28, x = p - y * 28;

    f32x4 f[4][4];
    #pragma unroll
    for (int i = 0; i < 4; i++) {
      const int iy = 2 * y - 1 + i;
      #pragma unroll
      for (int k = 0; k < 4; k++) {
        const int ix = 2 * x - 1 + k;
        f32x4 v = (f32x4)0.f;
        if (iy >= 0 && iy < 56 && ix >= 0 && ix < 56) {
          const u16x4 in4 = *(const u16x4*)&qkv[(size_t)(b * 3136 + iy * 56 + ix) * 2304 + t * 768 + 256 + g * 4];
          v[0] = bf2f(in4[0]); v[1] = bf2f(in4[1]); v[2] = bf2f(in4[2]); v[3] = bf2f(in4[3]);
        }
        f[i][k] = v;
      }
    }

    const f32x4 bias4 = *(const f32x4*)&c1b[g * 4];
    f32x4 best;
    #pragma unroll
    for (int j = 0; j < 4; j++) best[j] = -3.4e38f;

    #pragma unroll
    for (int dy = 0; dy < 2; dy++)
      #pragma unroll
      for (int dx = 0; dx < 2; dx++) {
        f32x4 c4 = bias4;
        #pragma unroll
        for (int ky = 0; ky < 3; ky++)
          #pragma unroll
          for (int kx = 0; kx < 3; kx++) {
            const f32x4 in4 = f[dy + ky][dx + kx];
            #pragma unroll
            for (int oc = 0; oc < 4; oc++) {
              const float* wp = &wg[oc * 36 + ky * 3 + kx];
              c4[oc] += in4[0] * wp[0] + in4[1] * wp[9] + in4[2] * wp[18] + in4[3] * wp[27];
            }
          }
        #pragma unroll
        for (int j = 0; j < 4; j++) best[j] = fmaxf(best[j], c4[j]);
      }
    u16x4 o4;
    #pragma unroll
    for (int j = 0; j < 4; j++) o4[j] = f2bf(best[j]);
    *(u16x4*)&g1[((size_t)bt * 784 + p) * 256 + g * 4] = o4;
  } else {
    const int p = (blockIdx.y - 196) * 4 + ty;
    const int y = p / 14, x = p - y * 14;

    const f32x4 bias4 = *(const f32x4*)&c2b[g * 4];
    f32x4 best;
    #pragma unroll
    for (int j = 0; j < 4; j++) best[j] = -3.4e38f;

    #pragma unroll
    for (int dy = 0; dy < 2; dy++)
      #pragma unroll
      for (int dx = 0; dx < 2; dx++) {
        const int py = 2 * y + dy, px = 2 * x + dx;
        f32x4 c4 = bias4;
        #pragma unroll
        for (int ky = 0; ky < 3; ky++) {
          const int iy = py * 2 - 2 + ky * 2;
          if (iy < 0 || iy >= 56) continue;
          #pragma unroll
          for (int kx = 0; kx < 3; kx++) {
            const int ix = px * 2 - 2 + kx * 2;
            if (ix < 0 || ix >= 56) continue;
            const u16x4 in4 = *(const u16x4*)&qkv[(size_t)(b * 3136 + iy * 56 + ix) * 2304 + t * 768 + 512 + g * 4];
            const float f0 = bf2f(in4[0]), f1 = bf2f(in4[1]), f2 = bf2f(in4[2]), f3 = bf2f(in4[3]);
            #pragma unroll
            for (int oc = 0; oc < 4; oc++) {
              const float* wp = &wg[oc * 36 + ky * 3 + kx];
              c4[oc] += f0 * wp[0] + f1 * wp[9] + f2 * wp[18] + f3 * wp[27];
            }
          }
        }
        #pragma unroll
        for (int j = 0; j < 4; j++) best[j] = fmaxf(best[j], c4[j]);
      }
    u16x4 o4;
    #pragma unroll
    for (int j = 0; j < 4; j++) o4[j] = f2bf(best[j]);
    *(u16x4*)&g2[((size_t)bt * 196 + p) * 256 + g * 4] = o4;
  }
}

// ---------------------------------------------------------------------------
// MFMA windowed attention, ALL scales in one launch. One WAVE per
// (b, region, head); 4 waves/block. Template-specialized bodies; block-range
// dispatch: [0,1024) scale0, [1024,1280) scale1, [1280,1344) scale2.
// ---------------------------------------------------------------------------
template<int SRC>
static __device__ __forceinline__
void attn_body(const u16* __restrict__ src, u16* __restrict__ fh,
               int side, int Hs, int head_base, int rep,
               int unit, int lane, char* vb, char* pb)
{
  const int nreg = side * side;
  const int h = unit & 3; unit >>= 2;
  const int r = unit % nreg;
  const int b = unit / nreg;
  const int hr = r / side, wr = r - hr * side;
  const int l15 = lane & 15, l4 = lane >> 4;

  auto gidx = [&](int t, int pp, int c) -> size_t {
    const int py = pp / 7, px = pp - py * 7;
    const int yy = hr * 7 + py, xx = wr * 7 + px;
    if (SRC == 0) return ((size_t)(b * 3136 + yy * 56 + xx)) * 2304 + (size_t)(t * 768 + h * 64 + c);
    else          return ((size_t)(b * 3 + t)) * ((size_t)Hs * Hs * 256) + (size_t)(yy * Hs + xx) * 256 + h * 64 + c;
  };

  // ---- stage V (t=2), rows clamped; swizzle byte ^= ((q>>3)&3)<<5 ----
  for (int i = lane; i < 1024; i += 64) {
    const int q = i >> 4, dc = i & 15;
    const int qs = q > 48 ? 48 : q;
    const u16x4 v4 = *(const u16x4*)&src[gidx(2, qs, dc * 4)];
    *(u16x4*)(vb + ((q * 128 + dc * 8) ^ (((q >> 3) & 3) << 5))) = v4;
  }

  // ---- QK^T ----
  f32x4 s[4][4];
  #pragma unroll
  for (int i = 0; i < 4; i++)
    #pragma unroll
    for (int j = 0; j < 4; j++) s[i][j] = (f32x4)0.f;

  bf16x8 bk[4][2];
  #pragma unroll
  for (int ni = 0; ni < 4; ni++) {
    const int q = ni * 16 + l15;
    const int qs = q > 48 ? 48 : q;
    #pragma unroll
    for (int ks = 0; ks < 2; ks++)
      bk[ni][ks] = *(const bf16x8*)&src[gidx(1, qs, ks * 32 + l4 * 8)];
  }
  #pragma unroll
  for (int mi = 0; mi < 4; mi++) {
    const int p = mi * 16 + l15;
    const int ps = p > 48 ? 48 : p;
    const bf16x8 a0 = *(const bf16x8*)&src[gidx(0, ps, l4 * 8)];
    const bf16x8 a1 = *(const bf16x8*)&src[gidx(0, ps, 32 + l4 * 8)];
    #pragma unroll
    for (int ni = 0; ni < 4; ni++) {
      s[mi][ni] = __builtin_amdgcn_mfma_f32_16x16x32_bf16(a0, bk[ni][0], s[mi][ni], 0, 0, 0);
      s[mi][ni] = __builtin_amdgcn_mfma_f32_16x16x32_bf16(a1, bk[ni][1], s[mi][ni], 0, 0, 0);
    }
  }

  // ---- mask cols q>=49, in-register softmax (unnormalized P) ----
  #pragma unroll
  for (int ni = 0; ni < 4; ni++) {
    const bool bad = (ni * 16 + l15) > 48;
    #pragma unroll
    for (int mi = 0; mi < 4; mi++)
      #pragma unroll
      for (int reg = 0; reg < 4; reg++)
        s[mi][ni][reg] = bad ? -1e30f : s[mi][ni][reg];
  }

  float inv[4][4];
  #pragma unroll
  for (int mi = 0; mi < 4; mi++)
    #pragma unroll
    for (int reg = 0; reg < 4; reg++) {
      float m = fmaxf(fmaxf(s[mi][0][reg], s[mi][1][reg]), fmaxf(s[mi][2][reg], s[mi][3][reg]));
      m = fmaxf(m, __shfl_xor(m, 1));
      m = fmaxf(m, __shfl_xor(m, 2));
      m = fmaxf(m, __shfl_xor(m, 4));
      m = fmaxf(m, __shfl_xor(m, 8));
      float partial = 0.f;
      #pragma unroll
      for (int ni = 0; ni < 4; ni++) {
        const float e = __expf((s[mi][ni][reg] - m) * 0.125f);
        s[mi][ni][reg] = e;
        partial += e;
      }
      partial += __shfl_xor(partial, 1);
      partial += __shfl_xor(partial, 2);
      partial += __shfl_xor(partial, 4);
      partial += __shfl_xor(partial, 8);
      inv[mi][reg] = 1.f / partial;
    }

  // ---- P -> LDS (bf16, XOR-swizzled rows) ----
  #pragma unroll
  for (int mi = 0; mi < 4; mi++)
    #pragma unroll
    for (int ni = 0; ni < 4; ni++)
      #pragma unroll
      for (int reg = 0; reg < 4; reg++) {
        const int row = mi * 16 + l4 * 4 + reg;
        const int col = ni * 16 + l15;
        *(u16*)(pb + ((row * 128 + col * 2) ^ ((row & 7) << 4))) = f2bf(s[mi][ni][reg]);
      }
  __syncthreads();

  // ---- PV ----
  f32x4 o[4][4];
  #pragma unroll
  for (int i = 0; i < 4; i++)
    #pragma unroll
    for (int j = 0; j < 4; j++) o[i][j] = (f32x4)0.f;

  #pragma unroll
  for (int ks = 0; ks < 2; ks++) {
    bf16x8 bv[4];
    #pragma unroll
    for (int ni = 0; ni < 4; ni++)
      #pragma unroll
      for (int j = 0; j < 8; j++) {
        const int q = ks * 32 + l4 * 8 + j;
        bv[ni][j] = *(const short*)(vb + ((q * 128 + (ni * 16 + l15) * 2) ^ (((q >> 3) & 3) << 5)));
      }
    #pragma unroll
    for (int mi = 0; mi < 4; mi++) {
      const int row = mi * 16 + l15;
      const bf16x8 pa = *(const bf16x8*)(pb + ((row * 128 + (ks * 4 + l4) * 16) ^ ((row & 7) << 4)));
      #pragma unroll
      for (int ni = 0; ni < 4; ni++)
        o[mi][ni] = __builtin_amdgcn_mfma_f32_16x16x32_bf16(pa, bv[ni], o[mi][ni], 0, 0, 0);
    }
  }

  // ---- epilogue: scale by 1/sum, bf16, replicate ----
  const int head = head_base + h;
  #pragma unroll
  for (int mi = 0; mi < 4; mi++)
    #pragma unroll
    for (int reg = 0; reg < 4; reg++) {
      const int p = mi * 16 + l4 * 4 + reg;
      if (p >= 49) continue;
      const float iv = inv[mi][reg];
      u16 hv[4];
      #pragma unroll
      for (int ni = 0; ni < 4; ni++) hv[ni] = f2bf(o[mi][ni][reg] * iv);
      for (int m = 0; m < rep; m++) {
        const size_t ob = ((size_t)b * 3136 + (size_t)(m * nreg + r) * 49 + p) * 768 + head * 64 + l15;
        #pragma unroll
        for (int ni = 0; ni < 4; ni++) fh[ob + ni * 16] = hv[ni];
      }
    }
}

__global__ __launch_bounds__(256)
void attn_all(const u16* __restrict__ qkv, const u16* __restrict__ g1,
              const u16* __restrict__ g2, u16* __restrict__ fh)
{
  __shared__ __align__(16) u16 sV[4][64 * 64];
  __shared__ __align__(16) u16 sP[4][64 * 64];
  const int tid = threadIdx.x;
  const int lane = tid & 63;
  const int w = tid >> 6;
  char* vb = (char*)sV[w];
  char* pb = (char*)sP[w];
  const int bid = blockIdx.x;

  if (bid < 1024) {
    attn_body<0>(qkv, fh, 8, 56, 0, 1,  bid * 4 + w,          lane, vb, pb);
  } else if (bid < 1280) {
    attn_body<1>(g1,  fh, 4, 28, 4, 4,  (bid - 1024) * 4 + w, lane, vb, pb);
  } else {
    attn_body<1>(g2,  fh, 2, 14, 8, 16, (bid - 1280) * 4 + w, lane, vb, pb);
  }
}

extern "C" void kernel_launch(void* const* d_in, const int* in_sizes, int n_in,
                              void* d_out, int out_size, void* d_ws, size_t ws_size,
                              hipStream_t stream)
{
  const float* x      = (const float*)d_in[0];
  const float* w_qkv  = (const float*)d_in[1];
  const float* w_proj = (const float*)d_in[2];
  const float* b_proj = (const float*)d_in[3];
  const float* c1w    = (const float*)d_in[4];
  const float* c1b    = (const float*)d_in[5];
  const float* c2w    = (const float*)d_in[6];
  const float* c2b    = (const float*)d_in[7];
  float* out = (float*)d_out;

  u16 *xh, *wqkvh, *wprojh, *qkvb, *g1, *g2, *fh;
  hipGetSymbolAddress((void**)&xh,     HIP_SYMBOL(g_xh));
  hipGetSymbolAddress((void**)&wqkvh,  HIP_SYMBOL(g_wqkvh));
  hipGetSymbolAddress((void**)&wprojh, HIP_SYMBOL(g_wprojh));
  hipGetSymbolAddress((void**)&qkvb,   HIP_SYMBOL(g_qkv));
  hipGetSymbolAddress((void**)&g1,     HIP_SYMBOL(g_g1));
  hipGetSymbolAddress((void**)&g2,     HIP_SYMBOL(g_g2));
  hipGetSymbolAddress((void**)&fh,     HIP_SYMBOL(g_fh));

  // 0) one-shot bf16 conversions (merged launch)
  cvt_bf16_3<<<2048, 256, 0, stream>>>(x, xh, 50176 * 768 / 4,
                                       w_qkv, wqkvh, 2304 * 768 / 4,
                                       w_proj, wprojh, 768 * 768 / 4);

  // 1) QKV GEMM (bf16): (50176,768)@(2304,768)^T -> qkv bf16
  gemm256<false, u16><<<(50176 / 256) * (2304 / 256), 512, 0, stream>>>(
      xh, wqkvh, nullptr, qkvb, 2304, 768, 2304 / 256);

  // 2) both convs in one launch (bf16 out)
  conv_all<<<dim3(48, 245), dim3(64, 4), 0, stream>>>(qkvb, c1w, c1b, g1, c2w, c2b, g2);

  // 3) all three attention scales in one launch -> fused bf16
  attn_all<<<1024 + 256 + 64, 256, 0, stream>>>(qkvb, g1, g2, fh);

  // 4) proj GEMM + bias -> out (f32)
  gemm256<true, float><<<(50176 / 256) * (768 / 256), 512, 0, stream>>>(
      fh, wprojh, b_proj, out, 768, 768, 768 / 256);
}